// Round 1
// baseline (527.476 us; speedup 1.0000x reference)
//
#include <hip/hip_runtime.h>

#define N_NODES 50000
#define N_EDGES 800000
#define IN_DIM 100
#define OUT_DIM 40

// ---------------- zero scratch (deg, cursor, colsum, colsq are contiguous) ----
__global__ void zero_kernel(int* p, int n) {
    int i = blockIdx.x * blockDim.x + threadIdx.x;
    if (i < n) p[i] = 0;
}

// ---------------- in-degree ----------------
__global__ void deg_kernel(const int* __restrict__ dst, int* __restrict__ deg) {
    int e = blockIdx.x * blockDim.x + threadIdx.x;
    if (e < N_EDGES) atomicAdd(&deg[dst[e]], 1);
}

// ---------------- exclusive scan of deg -> rowptr, plus norm ----------------
__global__ __launch_bounds__(1024) void scan_kernel(const int* __restrict__ deg,
                                                    int* __restrict__ rowptr,
                                                    float* __restrict__ norm) {
    __shared__ int partial[1024];
    __shared__ int block_off;
    int tid = threadIdx.x;
    if (tid == 0) block_off = 0;
    __syncthreads();
    for (int base = 0; base < N_NODES; base += 1024) {
        int i = base + tid;
        int d = (i < N_NODES) ? deg[i] : 0;
        partial[tid] = d;
        __syncthreads();
        for (int off = 1; off < 1024; off <<= 1) {
            int v = (tid >= off) ? partial[tid - off] : 0;
            __syncthreads();
            partial[tid] += v;
            __syncthreads();
        }
        if (i < N_NODES) {
            rowptr[i] = block_off + partial[tid] - d;           // exclusive
            norm[i] = 1.0f / sqrtf((float)max(d, 1));
        }
        __syncthreads();
        if (tid == 0) block_off += partial[1023];
        __syncthreads();
    }
    if (tid == 0) rowptr[N_NODES] = block_off;
}

// ---------------- counting-sort edges into CSR ----------------
__global__ void csr_fill_kernel(const int* __restrict__ src, const int* __restrict__ dst,
                                const int* __restrict__ rowptr, int* __restrict__ cursor,
                                int* __restrict__ csr) {
    int e = blockIdx.x * blockDim.x + threadIdx.x;
    if (e < N_EDGES) {
        int d = dst[e];
        int pos = rowptr[d] + atomicAdd(&cursor[d], 1);
        csr[pos] = src[e];
    }
}

// ---------------- one SGC hop, fully fused: out[n] = norm[n]*sum(h[src]*norm[src]) ----
__global__ __launch_bounds__(128) void spmm_kernel(const float* __restrict__ A,
                                                   const int* __restrict__ rowptr,
                                                   const int* __restrict__ csr,
                                                   const float* __restrict__ norm,
                                                   float* __restrict__ out) {
    int n = blockIdx.x;
    int tid = threadIdx.x;
    int beg = rowptr[n], end = rowptr[n + 1];
    __shared__ int sE[128];
    __shared__ float sN[128];
    float acc = 0.0f;
    for (int c = beg; c < end; c += 128) {
        int cnt = min(128, end - c);
        if (tid < cnt) {
            int s = csr[c + tid];
            sE[tid] = s;
            sN[tid] = norm[s];
        }
        __syncthreads();
        if (tid < IN_DIM) {
            for (int j = 0; j < cnt; ++j)
                acc += A[sE[j] * IN_DIM + tid] * sN[j];
        }
        __syncthreads();
    }
    if (tid < IN_DIM) out[n * IN_DIM + tid] = acc * norm[n];
}

// ---------------- per-feature sum / sumsq ----------------
__global__ __launch_bounds__(256) void col_stats_kernel(const float* __restrict__ h,
                                                        float* __restrict__ colsum,
                                                        float* __restrict__ colsq) {
    __shared__ float ssum[IN_DIM];
    __shared__ float ssq[IN_DIM];
    if (threadIdx.x < IN_DIM) { ssum[threadIdx.x] = 0.f; ssq[threadIdx.x] = 0.f; }
    __syncthreads();
    const int total = N_NODES * IN_DIM;
    for (int i = blockIdx.x * blockDim.x + threadIdx.x; i < total;
         i += gridDim.x * blockDim.x) {
        float v = h[i];
        int f = i % IN_DIM;
        atomicAdd(&ssum[f], v);
        atomicAdd(&ssq[f], v * v);
    }
    __syncthreads();
    if (threadIdx.x < IN_DIM) {
        atomicAdd(&colsum[threadIdx.x], ssum[threadIdx.x]);
        atomicAdd(&colsq[threadIdx.x], ssq[threadIdx.x]);
    }
}

// ---------------- fold standardize into W,b:  Wt[f][o]=W[o][f]/sigma_f, b' ----
__global__ __launch_bounds__(256) void prep_kernel(const float* __restrict__ colsum,
                                                   const float* __restrict__ colsq,
                                                   const float* __restrict__ W,
                                                   const float* __restrict__ b,
                                                   float* __restrict__ Wt,
                                                   float* __restrict__ bp) {
    __shared__ float smean[IN_DIM];
    __shared__ float sinv[IN_DIM];
    int t = threadIdx.x;
    const float Nf = (float)N_NODES;
    if (t < IN_DIM) {
        float m = colsum[t] / Nf;
        float var = (colsq[t] - Nf * m * m) / (Nf - 1.0f);
        var = fmaxf(var, 1e-20f);
        smean[t] = m;
        sinv[t] = 1.0f / sqrtf(var);
    }
    __syncthreads();
    for (int i = t; i < IN_DIM * OUT_DIM; i += 256) {
        int o = i % OUT_DIM, f = i / OUT_DIM;
        Wt[f * OUT_DIM + o] = W[o * IN_DIM + f] * sinv[f];
    }
    if (t < OUT_DIM) {
        float acc = b[t];
        for (int f = 0; f < IN_DIM; ++f)
            acc -= smean[f] * W[t * IN_DIM + f] * sinv[f];
        bp[t] = acc;
    }
}

// ---------------- final linear: out[n][o] = bp[o] + sum_f h[n][f]*Wt[f][o] ----
__global__ __launch_bounds__(256) void final_kernel(const float* __restrict__ h,
                                                    const float* __restrict__ Wt,
                                                    const float* __restrict__ bp,
                                                    float* __restrict__ out) {
    int t = blockIdx.x * blockDim.x + threadIdx.x;
    const int total = N_NODES * OUT_DIM;
    if (t >= total) return;
    int n = t / OUT_DIM;
    int o = t - n * OUT_DIM;
    const float* hr = h + n * IN_DIM;
    float acc = bp[o];
#pragma unroll 4
    for (int f = 0; f < IN_DIM; ++f)
        acc += hr[f] * Wt[f * OUT_DIM + o];
    out[t] = acc;
}

extern "C" void kernel_launch(void* const* d_in, const int* in_sizes, int n_in,
                              void* d_out, int out_size, void* d_ws, size_t ws_size,
                              hipStream_t stream) {
    const float* feat = (const float*)d_in[0];   // [50000,100]
    const float* W    = (const float*)d_in[1];   // [40,100]
    const float* b    = (const float*)d_in[2];   // [40]
    const int*   src  = (const int*)d_in[3];     // [800000]
    const int*   dst  = (const int*)d_in[4];     // [800000]
    float* out = (float*)d_out;                  // [50000,40]

    // workspace layout (16B-aligned chunks)
    char* w = (char*)d_ws;
    int*   deg    = (int*)w;    w += N_NODES * 4;            // 200000
    int*   cursor = (int*)w;    w += N_NODES * 4;            // 200000
    float* colsum = (float*)w;  w += 128 * 4;                // 512
    float* colsq  = (float*)w;  w += 128 * 4;                // 512
    // ---- end of zero region: (N_NODES*2 + 256) ints ----
    int*   rowptr = (int*)w;    w += 50004 * 4;              // 50001 used, padded
    float* norm   = (float*)w;  w += N_NODES * 4;
    int*   csr    = (int*)w;    w += N_EDGES * 4;
    float* Wt     = (float*)w;  w += IN_DIM * OUT_DIM * 4;
    float* bp     = (float*)w;  w += 64 * 4;
    float* bufA   = (float*)w;  w += (size_t)N_NODES * IN_DIM * 4;
    float* bufB   = (float*)w;  w += (size_t)N_NODES * IN_DIM * 4;

    // 1. zero {deg, cursor, colsum, colsq} (contiguous)
    {
        int nz = N_NODES * 2 + 256;
        zero_kernel<<<(nz + 255) / 256, 256, 0, stream>>>(deg, nz);
    }
    // 2. in-degree
    deg_kernel<<<(N_EDGES + 255) / 256, 256, 0, stream>>>(dst, deg);
    // 3. rowptr (exclusive scan) + norm
    scan_kernel<<<1, 1024, 0, stream>>>(deg, rowptr, norm);
    // 4. CSR fill
    csr_fill_kernel<<<(N_EDGES + 255) / 256, 256, 0, stream>>>(src, dst, rowptr, cursor, csr);
    // 5. three fused hops: feat -> A -> B -> A
    spmm_kernel<<<N_NODES, 128, 0, stream>>>(feat, rowptr, csr, norm, bufA);
    spmm_kernel<<<N_NODES, 128, 0, stream>>>(bufA, rowptr, csr, norm, bufB);
    spmm_kernel<<<N_NODES, 128, 0, stream>>>(bufB, rowptr, csr, norm, bufA);
    // 6. column stats on final h (bufA)
    col_stats_kernel<<<1024, 256, 0, stream>>>(bufA, colsum, colsq);
    // 7. fold mean/std into W', b'
    prep_kernel<<<1, 256, 0, stream>>>(colsum, colsq, W, b, Wt, bp);
    // 8. final linear
    {
        int total = N_NODES * OUT_DIM;
        final_kernel<<<(total + 255) / 256, 256, 0, stream>>>(bufA, Wt, bp, out);
    }
}

// Round 2
// 389.658 us; speedup vs baseline: 1.3537x; 1.3537x over previous
//
#include <hip/hip_runtime.h>

#define N_NODES 50000
#define N_EDGES 800000
#define IN_DIM 100
#define OUT_DIM 40
#define SCAN_B 512
#define NSCAN_BLK ((N_NODES + SCAN_B - 1) / SCAN_B)   // 98

// ---------------- zero scratch (deg, cursor, colsum, colsq contiguous) ----
__global__ void zero_kernel(int* p, int n) {
    int i = blockIdx.x * blockDim.x + threadIdx.x;
    if (i < n) p[i] = 0;
}

// ---------------- in-degree ----------------
__global__ void deg_kernel(const int* __restrict__ dst, int* __restrict__ deg) {
    int e = blockIdx.x * blockDim.x + threadIdx.x;
    if (e < N_EDGES) atomicAdd(&deg[dst[e]], 1);
}

// ---------------- scan phase 1: per-block exclusive scan + block sums + norms ----
__global__ __launch_bounds__(SCAN_B) void scan1_kernel(const int* __restrict__ deg,
                                                       int* __restrict__ rowptr,
                                                       float* __restrict__ norm,
                                                       float* __restrict__ norm2,
                                                       int* __restrict__ blocksum) {
    int i = blockIdx.x * SCAN_B + threadIdx.x;
    int lane = threadIdx.x & 63, wid = threadIdx.x >> 6;
    int d = (i < N_NODES) ? deg[i] : 0;
    int v = d;
#pragma unroll
    for (int off = 1; off < 64; off <<= 1) {
        int t = __shfl_up(v, off);
        if (lane >= off) v += t;
    }
    __shared__ int wsum[8];
    if (lane == 63) wsum[wid] = v;
    __syncthreads();
    if (threadIdx.x < 8) {
        int w = wsum[threadIdx.x];
#pragma unroll
        for (int off = 1; off < 8; off <<= 1) {
            int t = __shfl_up(w, off);
            if (lane >= off) w += t;
        }
        wsum[threadIdx.x] = w;   // inclusive wave sums
    }
    __syncthreads();
    int woff = wid ? wsum[wid - 1] : 0;
    int incl = woff + v;
    if (i < N_NODES) {
        rowptr[i] = incl - d;                     // block-local exclusive
        float n1 = 1.0f / sqrtf((float)max(d, 1));
        norm[i] = n1;
        norm2[i] = n1 * n1;
    }
    if (threadIdx.x == SCAN_B - 1) blocksum[blockIdx.x] = incl;
}

// ---------------- scan phase 2: scan the 98 block sums ----
__global__ __launch_bounds__(128) void scan2_kernel(const int* __restrict__ blocksum,
                                                    int* __restrict__ blockoff,
                                                    int* __restrict__ rowptr) {
    __shared__ int s[128];
    int t = threadIdx.x;
    int v = (t < NSCAN_BLK) ? blocksum[t] : 0;
    s[t] = v;
    __syncthreads();
    for (int off = 1; off < 128; off <<= 1) {
        int u = (t >= off) ? s[t - off] : 0;
        __syncthreads();
        s[t] += u;
        __syncthreads();
    }
    if (t < NSCAN_BLK) blockoff[t] = s[t] - v;    // exclusive
    if (t == 127) rowptr[N_NODES] = s[127];
}

// ---------------- scan phase 3: add block offsets ----
__global__ __launch_bounds__(SCAN_B) void scan3_kernel(int* __restrict__ rowptr,
                                                       const int* __restrict__ blockoff) {
    int i = blockIdx.x * SCAN_B + threadIdx.x;
    if (i < N_NODES) rowptr[i] += blockoff[blockIdx.x];
}

// ---------------- counting-sort edges into CSR ----------------
__global__ void csr_fill_kernel(const int* __restrict__ src, const int* __restrict__ dst,
                                const int* __restrict__ rowptr, int* __restrict__ cursor,
                                int* __restrict__ csr) {
    int e = blockIdx.x * blockDim.x + threadIdx.x;
    if (e < N_EDGES) {
        int d = dst[e];
        int pos = rowptr[d] + atomicAdd(&cursor[d], 1);
        csr[pos] = src[e];
    }
}

// ---------------- SGC hop.
// FIRST: out[n] = scale[n] * sum_s A[s]*norm[s]   (g1 = norm2 * S(norm*feat))
// else : out[n] = scale[n] * sum_s A[s]           (pure gather-sum)
template <bool FIRST>
__global__ __launch_bounds__(128) void spmm_kernel(const float* __restrict__ A,
                                                   const int* __restrict__ rowptr,
                                                   const int* __restrict__ csr,
                                                   const float* __restrict__ norm,
                                                   const float* __restrict__ scale,
                                                   float* __restrict__ out) {
    int n = blockIdx.x;
    int tid = threadIdx.x;
    int beg = rowptr[n], end = rowptr[n + 1];
    __shared__ int sE[128];
    __shared__ float sN[128];
    float acc = 0.0f;
    for (int c = beg; c < end; c += 128) {
        int cnt = min(128, end - c);
        if (tid < cnt) {
            int s = csr[c + tid];
            sE[tid] = s;
            if (FIRST) sN[tid] = norm[s];
        }
        __syncthreads();
        if (tid < IN_DIM) {
            for (int j = 0; j < cnt; ++j) {
                float a = A[(size_t)sE[j] * IN_DIM + tid];
                acc += FIRST ? a * sN[j] : a;
            }
        }
        __syncthreads();
    }
    if (tid < IN_DIM) out[n * IN_DIM + tid] = acc * scale[n];
}

// ---------------- per-feature sum/sumsq: fixed column per thread ----------------
#define CS_BLOCKS 625
#define CS_THREADS 256   // 625*256 = 160000, multiple of 100 -> f fixed per thread
__global__ __launch_bounds__(CS_THREADS) void col_stats_kernel(const float* __restrict__ h,
                                                               float* __restrict__ colsum,
                                                               float* __restrict__ colsq) {
    int gtid = blockIdx.x * CS_THREADS + threadIdx.x;
    const int stride = CS_BLOCKS * CS_THREADS;
    float sum = 0.f, sq = 0.f;
    for (int i = gtid; i < N_NODES * IN_DIM; i += stride) {
        float v = h[i];
        sum += v;
        sq += v * v;
    }
    __shared__ float ssum[IN_DIM], ssq[IN_DIM];
    if (threadIdx.x < IN_DIM) { ssum[threadIdx.x] = 0.f; ssq[threadIdx.x] = 0.f; }
    __syncthreads();
    int f = gtid % IN_DIM;
    atomicAdd(&ssum[f], sum);
    atomicAdd(&ssq[f], sq);
    __syncthreads();
    if (threadIdx.x < IN_DIM) {
        atomicAdd(&colsum[threadIdx.x], ssum[threadIdx.x]);
        atomicAdd(&colsq[threadIdx.x], ssq[threadIdx.x]);
    }
}

// ---------------- fold standardize into W,b ----------------
__global__ __launch_bounds__(256) void prep_kernel(const float* __restrict__ colsum,
                                                   const float* __restrict__ colsq,
                                                   const float* __restrict__ W,
                                                   const float* __restrict__ b,
                                                   float* __restrict__ Wt,
                                                   float* __restrict__ bp) {
    __shared__ float smean[IN_DIM];
    __shared__ float sinv[IN_DIM];
    int t = threadIdx.x;
    const float Nf = (float)N_NODES;
    if (t < IN_DIM) {
        float m = colsum[t] / Nf;
        float var = (colsq[t] - Nf * m * m) / (Nf - 1.0f);
        var = fmaxf(var, 1e-20f);
        smean[t] = m;
        sinv[t] = 1.0f / sqrtf(var);
    }
    __syncthreads();
    for (int i = t; i < IN_DIM * OUT_DIM; i += 256) {
        int o = i % OUT_DIM, f = i / OUT_DIM;
        Wt[f * OUT_DIM + o] = W[o * IN_DIM + f] * sinv[f];
    }
    if (t < OUT_DIM) {
        float acc = b[t];
        for (int f = 0; f < IN_DIM; ++f)
            acc -= smean[f] * W[t * IN_DIM + f] * sinv[f];
        bp[t] = acc;
    }
}

// ---------------- final linear with W' staged in LDS ----------------
__global__ __launch_bounds__(256) void final_kernel(const float* __restrict__ h,
                                                    const float* __restrict__ Wt,
                                                    const float* __restrict__ bp,
                                                    float* __restrict__ out) {
    __shared__ float sW[IN_DIM * OUT_DIM];   // 16 KB
    __shared__ float sb[OUT_DIM];
    for (int i = threadIdx.x; i < IN_DIM * OUT_DIM; i += 256) sW[i] = Wt[i];
    if (threadIdx.x < OUT_DIM) sb[threadIdx.x] = bp[threadIdx.x];
    __syncthreads();
    int t = blockIdx.x * 256 + threadIdx.x;
    if (t >= N_NODES * OUT_DIM) return;
    int n = t / OUT_DIM;
    int o = t - n * OUT_DIM;
    const float* hr = h + n * IN_DIM;
    float acc = sb[o];
#pragma unroll 4
    for (int f = 0; f < IN_DIM; ++f)
        acc += hr[f] * sW[f * OUT_DIM + o];
    out[t] = acc;
}

extern "C" void kernel_launch(void* const* d_in, const int* in_sizes, int n_in,
                              void* d_out, int out_size, void* d_ws, size_t ws_size,
                              hipStream_t stream) {
    const float* feat = (const float*)d_in[0];   // [50000,100]
    const float* W    = (const float*)d_in[1];   // [40,100]
    const float* b    = (const float*)d_in[2];   // [40]
    const int*   src  = (const int*)d_in[3];     // [800000]
    const int*   dst  = (const int*)d_in[4];     // [800000]
    float* out = (float*)d_out;                  // [50000,40]

    char* w = (char*)d_ws;
    int*   deg      = (int*)w;    w += N_NODES * 4;
    int*   cursor   = (int*)w;    w += N_NODES * 4;
    float* colsum   = (float*)w;  w += 128 * 4;
    float* colsq    = (float*)w;  w += 128 * 4;
    // ---- end of zero region: (N_NODES*2 + 256) ints ----
    int*   rowptr   = (int*)w;    w += 50004 * 4;
    float* norm     = (float*)w;  w += N_NODES * 4;
    float* norm2    = (float*)w;  w += N_NODES * 4;
    int*   blocksum = (int*)w;    w += 128 * 4;
    int*   blockoff = (int*)w;    w += 128 * 4;
    int*   csr      = (int*)w;    w += N_EDGES * 4;
    float* Wt       = (float*)w;  w += IN_DIM * OUT_DIM * 4;
    float* bp       = (float*)w;  w += 64 * 4;
    float* bufA     = (float*)w;  w += (size_t)N_NODES * IN_DIM * 4;
    float* bufB     = (float*)w;  w += (size_t)N_NODES * IN_DIM * 4;

    // 1. zero {deg, cursor, colsum, colsq}
    {
        int nz = N_NODES * 2 + 256;
        zero_kernel<<<(nz + 255) / 256, 256, 0, stream>>>(deg, nz);
    }
    // 2. in-degree
    deg_kernel<<<(N_EDGES + 255) / 256, 256, 0, stream>>>(dst, deg);
    // 3. rowptr (3-phase multi-block scan) + norm/norm2
    scan1_kernel<<<NSCAN_BLK, SCAN_B, 0, stream>>>(deg, rowptr, norm, norm2, blocksum);
    scan2_kernel<<<1, 128, 0, stream>>>(blocksum, blockoff, rowptr);
    scan3_kernel<<<NSCAN_BLK, SCAN_B, 0, stream>>>(rowptr, blockoff);
    // 4. CSR fill
    csr_fill_kernel<<<(N_EDGES + 255) / 256, 256, 0, stream>>>(src, dst, rowptr, cursor, csr);
    // 5. three hops with norm algebra folded:
    //    g1 = norm2 * S(norm*feat); g2 = norm2 * S(g1); h3 = norm * S(g2)
    spmm_kernel<true><<<N_NODES, 128, 0, stream>>>(feat, rowptr, csr, norm, norm2, bufA);
    spmm_kernel<false><<<N_NODES, 128, 0, stream>>>(bufA, rowptr, csr, norm, norm2, bufB);
    spmm_kernel<false><<<N_NODES, 128, 0, stream>>>(bufB, rowptr, csr, norm, norm, bufA);
    // 6. column stats on final h
    col_stats_kernel<<<CS_BLOCKS, CS_THREADS, 0, stream>>>(bufA, colsum, colsq);
    // 7. fold mean/std into W', b'
    prep_kernel<<<1, 256, 0, stream>>>(colsum, colsq, W, b, Wt, bp);
    // 8. final linear
    {
        int total = N_NODES * OUT_DIM;
        final_kernel<<<(total + 255) / 256, 256, 0, stream>>>(bufA, Wt, bp, out);
    }
}

// Round 3
// 305.035 us; speedup vs baseline: 1.7292x; 1.2774x over previous
//
#include <hip/hip_runtime.h>

#define N_NODES 50000
#define N_EDGES 800000
#define IN_DIM 100
#define OUT_DIM 40
#define ROW 50            // 50 dwords = 100 bf16 per node row
#define SCAN_B 512
#define NSCAN_BLK ((N_NODES + SCAN_B - 1) / SCAN_B)   // 98

typedef unsigned int uint;

// ---- bf16 helpers (packed pair in one dword) ----
__device__ __forceinline__ float bflo(uint u) { return __uint_as_float(u << 16); }
__device__ __forceinline__ float bfhi(uint u) { return __uint_as_float(u & 0xffff0000u); }
__device__ __forceinline__ uint packbf(float a, float b) {
    uint ua = __float_as_uint(a), ub = __float_as_uint(b);
    ua = (ua + 0x7fffu + ((ua >> 16) & 1u)) >> 16;      // RNE
    ub = (ub + 0x7fffu + ((ub >> 16) & 1u)) >> 16;
    return ua | (ub << 16);
}

// ---------------- zero scratch ----------------
__global__ void zero_kernel(int* p, int n) {
    int i = blockIdx.x * blockDim.x + threadIdx.x;
    if (i < n) p[i] = 0;
}

// zero the 3 pad rows (index N_NODES) of fs/bufA/bufB
__global__ void zero_pads_kernel(uint* fs, uint* bufA, uint* bufB) {
    int t = threadIdx.x;
    if (t < ROW) {
        fs[(size_t)N_NODES * ROW + t] = 0u;
        bufA[(size_t)N_NODES * ROW + t] = 0u;
        bufB[(size_t)N_NODES * ROW + t] = 0u;
    }
}

// ---------------- in-degree ----------------
__global__ void deg_kernel(const int* __restrict__ dst, int* __restrict__ deg) {
    int e = blockIdx.x * blockDim.x + threadIdx.x;
    if (e < N_EDGES) atomicAdd(&deg[dst[e]], 1);
}

// ---------------- scan phase 1 ----------------
__global__ __launch_bounds__(SCAN_B) void scan1_kernel(const int* __restrict__ deg,
                                                       int* __restrict__ rowptr,
                                                       float* __restrict__ norm,
                                                       float* __restrict__ norm2,
                                                       int* __restrict__ blocksum) {
    int i = blockIdx.x * SCAN_B + threadIdx.x;
    int lane = threadIdx.x & 63, wid = threadIdx.x >> 6;
    int d = (i < N_NODES) ? deg[i] : 0;
    int v = d;
#pragma unroll
    for (int off = 1; off < 64; off <<= 1) {
        int t = __shfl_up(v, off);
        if (lane >= off) v += t;
    }
    __shared__ int wsum[8];
    if (lane == 63) wsum[wid] = v;
    __syncthreads();
    if (threadIdx.x < 8) {
        int w = wsum[threadIdx.x];
#pragma unroll
        for (int off = 1; off < 8; off <<= 1) {
            int t = __shfl_up(w, off);
            if (lane >= off) w += t;
        }
        wsum[threadIdx.x] = w;
    }
    __syncthreads();
    int woff = wid ? wsum[wid - 1] : 0;
    int incl = woff + v;
    if (i < N_NODES) {
        rowptr[i] = incl - d;
        float n1 = 1.0f / sqrtf((float)max(d, 1));
        norm[i] = n1;
        norm2[i] = n1 * n1;
    }
    if (threadIdx.x == SCAN_B - 1) blocksum[blockIdx.x] = incl;
}

// ---------------- scan phase 2 ----------------
__global__ __launch_bounds__(128) void scan2_kernel(const int* __restrict__ blocksum,
                                                    int* __restrict__ blockoff,
                                                    int* __restrict__ rowptr) {
    __shared__ int s[128];
    int t = threadIdx.x;
    int v = (t < NSCAN_BLK) ? blocksum[t] : 0;
    s[t] = v;
    __syncthreads();
    for (int off = 1; off < 128; off <<= 1) {
        int u = (t >= off) ? s[t - off] : 0;
        __syncthreads();
        s[t] += u;
        __syncthreads();
    }
    if (t < NSCAN_BLK) blockoff[t] = s[t] - v;
    if (t == 127) rowptr[N_NODES] = s[127];
}

// ---------------- scan phase 3 ----------------
__global__ __launch_bounds__(SCAN_B) void scan3_kernel(int* __restrict__ rowptr,
                                                       const int* __restrict__ blockoff) {
    int i = blockIdx.x * SCAN_B + threadIdx.x;
    if (i < N_NODES) rowptr[i] += blockoff[blockIdx.x];
}

// ---------------- counting-sort edges into CSR ----------------
__global__ void csr_fill_kernel(const int* __restrict__ src, const int* __restrict__ dst,
                                const int* __restrict__ rowptr, int* __restrict__ cursor,
                                int* __restrict__ csr) {
    int e = blockIdx.x * blockDim.x + threadIdx.x;
    if (e < N_EDGES) {
        int d = dst[e];
        int pos = rowptr[d] + atomicAdd(&cursor[d], 1);
        csr[pos] = src[e];
    }
}

// ---------------- pre-scale: fs = bf16(norm ⊙ feat) ----------------
__global__ __launch_bounds__(256) void prescale_kernel(const float* __restrict__ feat,
                                                       const float* __restrict__ norm,
                                                       uint* __restrict__ fs) {
    int i = blockIdx.x * 256 + threadIdx.x;     // over N_NODES*ROW dword-pairs
    if (i < N_NODES * ROW) {
        int n = i / ROW;
        const float2 v = ((const float2*)feat)[i];
        float nm = norm[n];
        fs[i] = packbf(v.x * nm, v.y * nm);
    }
}

// ---------------- SGC hop: out[n] = bf16( scale[n] * sum_{s in N(n)} H[s] ) ----
// One 64-thread block per node. csr/rowptr reads are block-uniform -> scalar
// loads; 8-way unrolled gathers (dummy edges -> zero row N_NODES) give 8
// outstanding vector loads per wave. Lanes 50..63 clamp to lane 49's dword
// (same cacheline, no extra fetch) and never write.
__global__ __launch_bounds__(64) void spmm_kernel(const uint* __restrict__ H,
                                                  const int* __restrict__ rowptr,
                                                  const int* __restrict__ csr,
                                                  const float* __restrict__ scale,
                                                  uint* __restrict__ out) {
    const int n = blockIdx.x;
    const int l = threadIdx.x;
    const int ll = min(l, ROW - 1);
    const int beg = rowptr[n], end = rowptr[n + 1];
    float ax = 0.f, ay = 0.f;
    for (int j = beg; j < end; j += 8) {
        int s0 = csr[j];
        int s1 = (j + 1 < end) ? csr[j + 1] : N_NODES;
        int s2 = (j + 2 < end) ? csr[j + 2] : N_NODES;
        int s3 = (j + 3 < end) ? csr[j + 3] : N_NODES;
        int s4 = (j + 4 < end) ? csr[j + 4] : N_NODES;
        int s5 = (j + 5 < end) ? csr[j + 5] : N_NODES;
        int s6 = (j + 6 < end) ? csr[j + 6] : N_NODES;
        int s7 = (j + 7 < end) ? csr[j + 7] : N_NODES;
        uint u0 = H[(size_t)s0 * ROW + ll];
        uint u1 = H[(size_t)s1 * ROW + ll];
        uint u2 = H[(size_t)s2 * ROW + ll];
        uint u3 = H[(size_t)s3 * ROW + ll];
        uint u4 = H[(size_t)s4 * ROW + ll];
        uint u5 = H[(size_t)s5 * ROW + ll];
        uint u6 = H[(size_t)s6 * ROW + ll];
        uint u7 = H[(size_t)s7 * ROW + ll];
        ax += bflo(u0); ay += bfhi(u0);
        ax += bflo(u1); ay += bfhi(u1);
        ax += bflo(u2); ay += bfhi(u2);
        ax += bflo(u3); ay += bfhi(u3);
        ax += bflo(u4); ay += bfhi(u4);
        ax += bflo(u5); ay += bfhi(u5);
        ax += bflo(u6); ay += bfhi(u6);
        ax += bflo(u7); ay += bfhi(u7);
    }
    if (l < ROW) {
        float sc = scale[n];
        out[(size_t)n * ROW + l] = packbf(ax * sc, ay * sc);
    }
}

// ---------------- per-feature sum/sumsq over bf16 h3 ----------------
#define CS_BLOCKS 625
#define CS_THREADS 256   // 160000 threads, 160000 % 50 == 0 -> fixed pair per thread
__global__ __launch_bounds__(CS_THREADS) void col_stats_kernel(const uint* __restrict__ h,
                                                               float* __restrict__ colsum,
                                                               float* __restrict__ colsq) {
    int gtid = blockIdx.x * CS_THREADS + threadIdx.x;
    const int stride = CS_BLOCKS * CS_THREADS;
    float s0 = 0.f, s1 = 0.f, q0 = 0.f, q1 = 0.f;
    for (int i = gtid; i < N_NODES * ROW; i += stride) {
        uint u = h[i];
        float a = bflo(u), b = bfhi(u);
        s0 += a; s1 += b; q0 += a * a; q1 += b * b;
    }
    __shared__ float ssum[IN_DIM], ssq[IN_DIM];
    if (threadIdx.x < IN_DIM) { ssum[threadIdx.x] = 0.f; ssq[threadIdx.x] = 0.f; }
    __syncthreads();
    int p = gtid % ROW;
    atomicAdd(&ssum[2 * p], s0);
    atomicAdd(&ssum[2 * p + 1], s1);
    atomicAdd(&ssq[2 * p], q0);
    atomicAdd(&ssq[2 * p + 1], q1);
    __syncthreads();
    if (threadIdx.x < IN_DIM) {
        atomicAdd(&colsum[threadIdx.x], ssum[threadIdx.x]);
        atomicAdd(&colsq[threadIdx.x], ssq[threadIdx.x]);
    }
}

// ---------------- fold standardize into W,b ----------------
__global__ __launch_bounds__(256) void prep_kernel(const float* __restrict__ colsum,
                                                   const float* __restrict__ colsq,
                                                   const float* __restrict__ W,
                                                   const float* __restrict__ b,
                                                   float* __restrict__ Wt,
                                                   float* __restrict__ bp) {
    __shared__ float smean[IN_DIM];
    __shared__ float sinv[IN_DIM];
    int t = threadIdx.x;
    const float Nf = (float)N_NODES;
    if (t < IN_DIM) {
        float m = colsum[t] / Nf;
        float var = (colsq[t] - Nf * m * m) / (Nf - 1.0f);
        var = fmaxf(var, 1e-20f);
        smean[t] = m;
        sinv[t] = 1.0f / sqrtf(var);
    }
    __syncthreads();
    for (int i = t; i < IN_DIM * OUT_DIM; i += 256) {
        int o = i % OUT_DIM, f = i / OUT_DIM;
        Wt[f * OUT_DIM + o] = W[o * IN_DIM + f] * sinv[f];
    }
    if (t < OUT_DIM) {
        float acc = b[t];
        for (int f = 0; f < IN_DIM; ++f)
            acc -= smean[f] * W[t * IN_DIM + f] * sinv[f];
        bp[t] = acc;
    }
}

// ---------------- final linear over bf16 h3, W' staged in LDS ----------------
__global__ __launch_bounds__(256) void final_kernel(const uint* __restrict__ h,
                                                    const float* __restrict__ Wt,
                                                    const float* __restrict__ bp,
                                                    float* __restrict__ out) {
    __shared__ float sW[IN_DIM * OUT_DIM];   // 16 KB
    __shared__ float sb[OUT_DIM];
    for (int i = threadIdx.x; i < IN_DIM * OUT_DIM; i += 256) sW[i] = Wt[i];
    if (threadIdx.x < OUT_DIM) sb[threadIdx.x] = bp[threadIdx.x];
    __syncthreads();
    int t = blockIdx.x * 256 + threadIdx.x;
    if (t >= N_NODES * OUT_DIM) return;
    int n = t / OUT_DIM;
    int o = t - n * OUT_DIM;
    const uint* hr = h + (size_t)n * ROW;
    float acc = sb[o];
#pragma unroll 10
    for (int p = 0; p < ROW; ++p) {
        uint u = hr[p];
        acc += bflo(u) * sW[(2 * p) * OUT_DIM + o];
        acc += bfhi(u) * sW[(2 * p + 1) * OUT_DIM + o];
    }
    out[t] = acc;
}

extern "C" void kernel_launch(void* const* d_in, const int* in_sizes, int n_in,
                              void* d_out, int out_size, void* d_ws, size_t ws_size,
                              hipStream_t stream) {
    const float* feat = (const float*)d_in[0];   // [50000,100]
    const float* W    = (const float*)d_in[1];   // [40,100]
    const float* b    = (const float*)d_in[2];   // [40]
    const int*   src  = (const int*)d_in[3];     // [800000]
    const int*   dst  = (const int*)d_in[4];     // [800000]
    float* out = (float*)d_out;                  // [50000,40]

    char* w = (char*)d_ws;
    int*   deg      = (int*)w;    w += N_NODES * 4;
    int*   cursor   = (int*)w;    w += N_NODES * 4;
    float* colsum   = (float*)w;  w += 128 * 4;
    float* colsq    = (float*)w;  w += 128 * 4;
    // ---- end of zero region: (N_NODES*2 + 256) ints ----
    int*   rowptr   = (int*)w;    w += 50004 * 4;
    float* norm     = (float*)w;  w += N_NODES * 4;
    float* norm2    = (float*)w;  w += N_NODES * 4;
    int*   blocksum = (int*)w;    w += 128 * 4;
    int*   blockoff = (int*)w;    w += 128 * 4;
    int*   csr      = (int*)w;    w += N_EDGES * 4;
    float* Wt       = (float*)w;  w += IN_DIM * OUT_DIM * 4;
    float* bp       = (float*)w;  w += 64 * 4;
    const size_t HB = ((size_t)(N_NODES + 1) * ROW + 16) * 4;  // bf16 row buffers + pad row
    uint*  fs       = (uint*)w;   w += HB;
    uint*  bufA     = (uint*)w;   w += HB;
    uint*  bufB     = (uint*)w;   w += HB;

    // 1. zero {deg, cursor, colsum, colsq} + pad rows
    {
        int nz = N_NODES * 2 + 256;
        zero_kernel<<<(nz + 255) / 256, 256, 0, stream>>>(deg, nz);
        zero_pads_kernel<<<1, 64, 0, stream>>>(fs, bufA, bufB);
    }
    // 2. in-degree
    deg_kernel<<<(N_EDGES + 255) / 256, 256, 0, stream>>>(dst, deg);
    // 3. rowptr (3-phase scan) + norm/norm2
    scan1_kernel<<<NSCAN_BLK, SCAN_B, 0, stream>>>(deg, rowptr, norm, norm2, blocksum);
    scan2_kernel<<<1, 128, 0, stream>>>(blocksum, blockoff, rowptr);
    scan3_kernel<<<NSCAN_BLK, SCAN_B, 0, stream>>>(rowptr, blockoff);
    // 4. CSR fill
    csr_fill_kernel<<<(N_EDGES + 255) / 256, 256, 0, stream>>>(src, dst, rowptr, cursor, csr);
    // 5. pre-scale feat by norm into bf16
    prescale_kernel<<<(N_NODES * ROW + 255) / 256, 256, 0, stream>>>(feat, norm, fs);
    // 6. three hops: g1 = norm2*S(fs); g2 = norm2*S(g1); h3 = norm*S(g2)
    spmm_kernel<<<N_NODES, 64, 0, stream>>>(fs, rowptr, csr, norm2, bufA);
    spmm_kernel<<<N_NODES, 64, 0, stream>>>(bufA, rowptr, csr, norm2, bufB);
    spmm_kernel<<<N_NODES, 64, 0, stream>>>(bufB, rowptr, csr, norm, bufA);
    // 7. column stats on bf16 h3
    col_stats_kernel<<<CS_BLOCKS, CS_THREADS, 0, stream>>>(bufA, colsum, colsq);
    // 8. fold mean/std into W', b'
    prep_kernel<<<1, 256, 0, stream>>>(colsum, colsq, W, b, Wt, bp);
    // 9. final linear
    {
        int total = N_NODES * OUT_DIM;
        final_kernel<<<(total + 255) / 256, 256, 0, stream>>>(bufA, Wt, bp, out);
    }
}